// Round 1
// baseline (4307.079 us; speedup 1.0000x reference)
//
#include <hip/hip_runtime.h>

#define N_NODES 50000
#define N_EDGES 800000
#define IN_CH 128
#define HID 256
#define PROJ 128
#define N_GRAPHS 512

// ---------------------------------------------------------------------------
// Scatter-add: agg[dst] += feat[src], C channels, float4 vectorized gather,
// per-float atomicAdd scatter. C/4 lanes per edge.
// ---------------------------------------------------------------------------
template <int C>
__global__ __launch_bounds__(256) void scatter_add_kernel(
    const float* __restrict__ feat, const int* __restrict__ src,
    const int* __restrict__ dst, float* __restrict__ agg) {
  constexpr unsigned LPE = C / 4;  // float4 lanes per edge (32 or 64)
  unsigned gid = blockIdx.x * 256u + threadIdx.x;
  if (gid >= (unsigned)N_EDGES * LPE) return;
  unsigned e = gid / LPE;
  unsigned c4 = gid % LPE;
  int s = src[e];
  int d = dst[e];
  float4 v = reinterpret_cast<const float4*>(feat)[(size_t)s * LPE + c4];
  float* out = agg + (size_t)d * C + (size_t)c4 * 4;
  atomicAdd(out + 0, v.x);
  atomicAdd(out + 1, v.y);
  atomicAdd(out + 2, v.z);
  atomicAdd(out + 3, v.w);
}

// ---------------------------------------------------------------------------
// Row-block GEMM: C[m][n] = act( (A[m] + Agg[m]) . W[:,n] + bias[n] )
// blockDim.x == N (one thread per output column), R rows per block staged in
// LDS (broadcast reads). W[k*N + tid] is coalesced; W traffic amortized by R.
// ---------------------------------------------------------------------------
template <int K, int N, int R, bool ADD_AGG, bool RELU>
__global__ void gin_linear_kernel(const float* __restrict__ A,
                                  const float* __restrict__ Agg,
                                  const float* __restrict__ W,
                                  const float* __restrict__ bias,
                                  float* __restrict__ Cout, int M) {
  __shared__ float As[R][K];
  const int row0 = blockIdx.x * R;
  const int tid = threadIdx.x;  // 0..N-1
  // cooperative load of R rows (+agg) into LDS
  for (int idx = tid; idx < R * K; idx += N) {
    int r = idx / K;
    int k = idx % K;
    int m = row0 + r;
    float v = 0.f;
    if (m < M) {
      v = A[(size_t)m * K + k];
      if (ADD_AGG) v += Agg[(size_t)m * K + k];
    }
    As[r][k] = v;
  }
  __syncthreads();
  float acc[R];
#pragma unroll
  for (int r = 0; r < R; ++r) acc[r] = bias[tid];
  for (int k = 0; k < K; ++k) {
    float w = W[k * N + tid];
#pragma unroll
    for (int r = 0; r < R; ++r) acc[r] = fmaf(As[r][k], w, acc[r]);
  }
#pragma unroll
  for (int r = 0; r < R; ++r) {
    int m = row0 + r;
    if (m < M) {
      float v = acc[r];
      if (RELU) v = fmaxf(v, 0.f);
      Cout[(size_t)m * N + tid] = v;
    }
  }
}

// ---------------------------------------------------------------------------
// Mean-pool per graph. batch is sorted -> binary search segment bounds.
// One block per graph, one thread per channel.
// ---------------------------------------------------------------------------
__global__ __launch_bounds__(HID) void pool_kernel(
    const float* __restrict__ h, const int* __restrict__ batch,
    float* __restrict__ hgraph) {
  const int g = blockIdx.x;
  const int c = threadIdx.x;
  auto lower_bound = [&](int key) {
    int lo = 0, hi = N_NODES;
    while (lo < hi) {
      int mid = (lo + hi) >> 1;
      if (batch[mid] < key) lo = mid + 1; else hi = mid;
    }
    return lo;
  };
  const int s = lower_bound(g);
  const int e = lower_bound(g + 1);
  float acc = 0.f;
  for (int n = s; n < e; ++n) acc += h[(size_t)n * HID + c];
  float cnt = fmaxf((float)(e - s), 1.0f);
  hgraph[g * HID + c] = acc / cnt;
}

// ---------------------------------------------------------------------------
extern "C" void kernel_launch(void* const* d_in, const int* in_sizes, int n_in,
                              void* d_out, int out_size, void* d_ws,
                              size_t ws_size, hipStream_t stream) {
  const float* x = (const float*)d_in[0];
  const int* edge = (const int*)d_in[1];
  const int* batch = (const int*)d_in[2];
  const float* W1 = (const float*)d_in[3];
  const float* b1 = (const float*)d_in[4];
  const float* W2 = (const float*)d_in[5];
  const float* b2 = (const float*)d_in[6];
  const float* P1 = (const float*)d_in[7];
  const float* pb1 = (const float*)d_in[8];
  const float* P2 = (const float*)d_in[9];
  const float* pb2 = (const float*)d_in[10];
  const int* src = edge;
  const int* dst = edge + N_EDGES;

  char* ws = (char*)d_ws;
  const size_t AGG_BYTES = (size_t)N_NODES * HID * 4;  // 51.2 MB (layer1 uses 128 cols)
  float* agg = (float*)ws;
  float* h1 = (float*)(ws + AGG_BYTES);
  float* h2 = (float*)(ws + 2 * AGG_BYTES);
  float* hg = (float*)(ws + 3 * AGG_BYTES);
  float* t1 = (float*)(ws + 3 * AGG_BYTES + (size_t)N_GRAPHS * HID * 4);
  float* z = (float*)d_out;

  // Layer 1: agg = scatter(x); h1 = relu((x+agg) @ W1 + b1)
  hipMemsetAsync(agg, 0, (size_t)N_NODES * IN_CH * 4, stream);
  {
    unsigned total = (unsigned)N_EDGES * (IN_CH / 4);
    scatter_add_kernel<IN_CH><<<(total + 255) / 256, 256, 0, stream>>>(x, src, dst, agg);
  }
  gin_linear_kernel<IN_CH, HID, 8, true, true>
      <<<(N_NODES + 7) / 8, HID, 0, stream>>>(x, agg, W1, b1, h1, N_NODES);

  // Layer 2: agg = scatter(h1); h2 = relu((h1+agg) @ W2 + b2)
  hipMemsetAsync(agg, 0, (size_t)N_NODES * HID * 4, stream);
  {
    unsigned total = (unsigned)N_EDGES * (HID / 4);
    scatter_add_kernel<HID><<<(total + 255) / 256, 256, 0, stream>>>(h1, src, dst, agg);
  }
  gin_linear_kernel<HID, HID, 8, true, true>
      <<<(N_NODES + 7) / 8, HID, 0, stream>>>(h1, agg, W2, b2, h2, N_NODES);

  // Mean pool (batch sorted)
  pool_kernel<<<N_GRAPHS, HID, 0, stream>>>(h2, batch, hg);

  // Projection head: z = relu(hg @ P1 + pb1) @ P2 + pb2
  gin_linear_kernel<HID, HID, 8, false, true>
      <<<(N_GRAPHS + 7) / 8, HID, 0, stream>>>(hg, nullptr, P1, pb1, t1, N_GRAPHS);
  gin_linear_kernel<HID, PROJ, 8, false, false>
      <<<(N_GRAPHS + 7) / 8, PROJ, 0, stream>>>(t1, nullptr, P2, pb2, z, N_GRAPHS);
}

// Round 2
// 673.989 us; speedup vs baseline: 6.3904x; 6.3904x over previous
//
#include <hip/hip_runtime.h>

#define N_NODES 50000
#define N_EDGES 800000
#define IN_CH 128
#define HID 256
#define PROJ 128
#define N_GRAPHS 512

// ---------------------------------------------------------------------------
// CSR build: count in-degree, exclusive scan, fill edge lists (src per dst).
// ---------------------------------------------------------------------------
__global__ __launch_bounds__(256) void count_kernel(const int* __restrict__ dst,
                                                    int* __restrict__ cnt) {
  int e = blockIdx.x * 256 + threadIdx.x;
  if (e < N_EDGES) atomicAdd(&cnt[dst[e]], 1);
}

// Single-block chunked Hillis-Steele exclusive scan: ptr[i] = sum_{j<i} cnt[j],
// ptr[N_NODES] = total.
__global__ __launch_bounds__(1024) void scan_kernel(const int* __restrict__ cnt,
                                                    int* __restrict__ ptr) {
  __shared__ int lds[1024];
  __shared__ int s_carry;
  const int tid = threadIdx.x;
  if (tid == 0) s_carry = 0;
  __syncthreads();
  for (int base = 0; base < N_NODES; base += 1024) {
    const int carry = s_carry;
    const int i = base + tid;
    const int v = (i < N_NODES) ? cnt[i] : 0;
    lds[tid] = v;
    __syncthreads();
    for (int off = 1; off < 1024; off <<= 1) {
      int t = (tid >= off) ? lds[tid - off] : 0;
      __syncthreads();
      lds[tid] += t;
      __syncthreads();
    }
    if (i < N_NODES) ptr[i] = carry + lds[tid] - v;
    __syncthreads();
    if (tid == 1023) s_carry = carry + lds[1023];
    __syncthreads();
  }
  if (tid == 0) ptr[N_NODES] = s_carry;
}

__global__ __launch_bounds__(256) void fill_kernel(const int* __restrict__ src,
                                                   const int* __restrict__ dst,
                                                   int* __restrict__ cursor,
                                                   int* __restrict__ esrc) {
  int e = blockIdx.x * 256 + threadIdx.x;
  if (e < N_EDGES) {
    int pos = atomicAdd(&cursor[dst[e]], 1);
    esrc[pos] = src[e];
  }
}

// ---------------------------------------------------------------------------
// Pull-mode aggregation with fused self-term:
//   out[n] = feat[n] + sum_{e in [ptr[n],ptr[n+1])} feat[esrc[e]]
// One wave (64 lanes) per node; lanes hold the channel vector in registers.
// C=256 -> float4/lane, C=128 -> float2/lane. Gather rows are coalesced.
// ---------------------------------------------------------------------------
template <int C>
__global__ __launch_bounds__(256) void gather_agg_kernel(
    const float* __restrict__ feat, const int* __restrict__ ptr,
    const int* __restrict__ esrc, float* __restrict__ out) {
  const int wave = threadIdx.x >> 6;
  const int lane = threadIdx.x & 63;
  const int node = blockIdx.x * 4 + wave;
  if (node >= N_NODES) return;
  const int beg = ptr[node], end = ptr[node + 1];
  if constexpr (C == 256) {
    const float4* f4 = reinterpret_cast<const float4*>(feat);
    float4 acc = f4[(size_t)node * 64 + lane];
    for (int e = beg; e < end; ++e) {
      int s = esrc[e];
      float4 v = f4[(size_t)s * 64 + lane];
      acc.x += v.x; acc.y += v.y; acc.z += v.z; acc.w += v.w;
    }
    reinterpret_cast<float4*>(out)[(size_t)node * 64 + lane] = acc;
  } else {
    const float2* f2 = reinterpret_cast<const float2*>(feat);
    float2 acc = f2[(size_t)node * 64 + lane];
    for (int e = beg; e < end; ++e) {
      int s = esrc[e];
      float2 v = f2[(size_t)s * 64 + lane];
      acc.x += v.x; acc.y += v.y;
    }
    reinterpret_cast<float2*>(out)[(size_t)node * 64 + lane] = acc;
  }
}

// ---------------------------------------------------------------------------
// Row-block GEMM: C[m][n] = act( A[m] . W[:,n] + bias[n] )
// blockDim.x == N (one thread per output column), R rows staged in LDS.
// ---------------------------------------------------------------------------
template <int K, int N, int R, bool RELU>
__global__ void gin_linear_kernel(const float* __restrict__ A,
                                  const float* __restrict__ W,
                                  const float* __restrict__ bias,
                                  float* __restrict__ Cout, int M) {
  __shared__ float As[R][K];
  const int row0 = blockIdx.x * R;
  const int tid = threadIdx.x;  // 0..N-1
  for (int idx = tid; idx < R * K; idx += N) {
    int r = idx / K;
    int k = idx % K;
    int m = row0 + r;
    As[r][k] = (m < M) ? A[(size_t)m * K + k] : 0.f;
  }
  __syncthreads();
  float acc[R];
#pragma unroll
  for (int r = 0; r < R; ++r) acc[r] = bias[tid];
  for (int k = 0; k < K; ++k) {
    float w = W[k * N + tid];
#pragma unroll
    for (int r = 0; r < R; ++r) acc[r] = fmaf(As[r][k], w, acc[r]);
  }
#pragma unroll
  for (int r = 0; r < R; ++r) {
    int m = row0 + r;
    if (m < M) {
      float v = acc[r];
      if (RELU) v = fmaxf(v, 0.f);
      Cout[(size_t)m * N + tid] = v;
    }
  }
}

// ---------------------------------------------------------------------------
// Mean-pool per graph. batch is sorted -> binary search segment bounds.
// ---------------------------------------------------------------------------
__global__ __launch_bounds__(HID) void pool_kernel(
    const float* __restrict__ h, const int* __restrict__ batch,
    float* __restrict__ hgraph) {
  const int g = blockIdx.x;
  const int c = threadIdx.x;
  auto lower_bound = [&](int key) {
    int lo = 0, hi = N_NODES;
    while (lo < hi) {
      int mid = (lo + hi) >> 1;
      if (batch[mid] < key) lo = mid + 1; else hi = mid;
    }
    return lo;
  };
  const int s = lower_bound(g);
  const int e = lower_bound(g + 1);
  float acc = 0.f;
  for (int n = s; n < e; ++n) acc += h[(size_t)n * HID + c];
  float cnt = fmaxf((float)(e - s), 1.0f);
  hgraph[g * HID + c] = acc / cnt;
}

// ---------------------------------------------------------------------------
extern "C" void kernel_launch(void* const* d_in, const int* in_sizes, int n_in,
                              void* d_out, int out_size, void* d_ws,
                              size_t ws_size, hipStream_t stream) {
  const float* x = (const float*)d_in[0];
  const int* edge = (const int*)d_in[1];
  const int* batch = (const int*)d_in[2];
  const float* W1 = (const float*)d_in[3];
  const float* b1 = (const float*)d_in[4];
  const float* W2 = (const float*)d_in[5];
  const float* b2 = (const float*)d_in[6];
  const float* P1 = (const float*)d_in[7];
  const float* pb1 = (const float*)d_in[8];
  const float* P2 = (const float*)d_in[9];
  const float* pb2 = (const float*)d_in[10];
  const int* src = edge;
  const int* dst = edge + N_EDGES;

  char* ws = (char*)d_ws;
  size_t off = 0;
  auto alloc = [&](size_t bytes) {
    void* p = ws + off;
    off += (bytes + 255) & ~(size_t)255;
    return p;
  };
  float* xa = (float*)alloc((size_t)N_NODES * IN_CH * 4);   // x + agg1
  float* h1 = (float*)alloc((size_t)N_NODES * HID * 4);     // layer1 out, later h2
  float* ha = (float*)alloc((size_t)N_NODES * HID * 4);     // h1 + agg2
  float* hg = (float*)alloc((size_t)N_GRAPHS * HID * 4);
  float* t1 = (float*)alloc((size_t)N_GRAPHS * HID * 4);
  int* ptr = (int*)alloc((size_t)(N_NODES + 1) * 4);
  int* cursor = (int*)alloc((size_t)(N_NODES + 1) * 4);     // also the count buf
  int* esrc = (int*)alloc((size_t)N_EDGES * 4);
  float* z = (float*)d_out;

  const int EB = (N_EDGES + 255) / 256;

  // --- CSR build (dst-indexed) ---
  hipMemsetAsync(cursor, 0, (size_t)N_NODES * 4, stream);
  count_kernel<<<EB, 256, 0, stream>>>(dst, cursor);
  scan_kernel<<<1, 1024, 0, stream>>>(cursor, ptr);
  hipMemcpyAsync(cursor, ptr, (size_t)N_NODES * 4, hipMemcpyDeviceToDevice, stream);
  fill_kernel<<<EB, 256, 0, stream>>>(src, dst, cursor, esrc);

  // --- Layer 1: xa = x + gather(x); h1 = relu(xa @ W1 + b1) ---
  gather_agg_kernel<IN_CH>
      <<<(N_NODES + 3) / 4, 256, 0, stream>>>(x, ptr, esrc, xa);
  gin_linear_kernel<IN_CH, HID, 8, true>
      <<<(N_NODES + 7) / 8, HID, 0, stream>>>(xa, W1, b1, h1, N_NODES);

  // --- Layer 2: ha = h1 + gather(h1); h2 = relu(ha @ W2 + b2) (h2 -> h1 buf) ---
  gather_agg_kernel<HID>
      <<<(N_NODES + 3) / 4, 256, 0, stream>>>(h1, ptr, esrc, ha);
  gin_linear_kernel<HID, HID, 8, true>
      <<<(N_NODES + 7) / 8, HID, 0, stream>>>(ha, W2, b2, h1, N_NODES);

  // --- Mean pool (batch sorted) ---
  pool_kernel<<<N_GRAPHS, HID, 0, stream>>>(h1, batch, hg);

  // --- Projection head ---
  gin_linear_kernel<HID, HID, 8, true>
      <<<(N_GRAPHS + 7) / 8, HID, 0, stream>>>(hg, P1, pb1, t1, N_GRAPHS);
  gin_linear_kernel<HID, PROJ, 8, false>
      <<<(N_GRAPHS + 7) / 8, PROJ, 0, stream>>>(t1, P2, pb2, z, N_GRAPHS);
}

// Round 3
// 420.772 us; speedup vs baseline: 10.2361x; 1.6018x over previous
//
#include <hip/hip_runtime.h>
#include <hip/hip_bf16.h>

#define N_NODES 50000
#define N_EDGES 800000
#define IN_CH 128
#define HID 256
#define PROJ 128
#define N_GRAPHS 512

typedef short bf16x8 __attribute__((ext_vector_type(8)));
typedef float f32x4 __attribute__((ext_vector_type(4)));

__device__ inline float bf2f(unsigned short u) {
  union { unsigned int i; float f; } x;
  x.i = ((unsigned int)u) << 16;
  return x.f;
}
__device__ inline unsigned short f2bf(float f) {
  __hip_bfloat16 h = __float2bfloat16(f);  // RNE
  return *reinterpret_cast<unsigned short*>(&h);
}
__device__ inline void load_lds16(const void* g, void* l) {
  __builtin_amdgcn_global_load_lds(
      (const __attribute__((address_space(1))) void*)g,
      (__attribute__((address_space(3))) void*)l, 16, 0, 0);
}

// ---------------------------------------------------------------------------
// CSR build
// ---------------------------------------------------------------------------
__global__ __launch_bounds__(256) void count_kernel(const int* __restrict__ dst,
                                                    int* __restrict__ cnt) {
  int e = blockIdx.x * 256 + threadIdx.x;
  if (e < N_EDGES) atomicAdd(&cnt[dst[e]], 1);
}

// per-block exclusive scan of 256 elems; block sum out
__global__ __launch_bounds__(256) void scan1_kernel(const int* __restrict__ cnt,
                                                    int* __restrict__ ptr,
                                                    int* __restrict__ bsum) {
  __shared__ int lds[256];
  const int tid = threadIdx.x;
  const int i = blockIdx.x * 256 + tid;
  int v = (i < N_NODES) ? cnt[i] : 0;
  lds[tid] = v;
  __syncthreads();
  for (int off = 1; off < 256; off <<= 1) {
    int t = (tid >= off) ? lds[tid - off] : 0;
    __syncthreads();
    lds[tid] += t;
    __syncthreads();
  }
  if (i < N_NODES) ptr[i] = lds[tid] - v;  // exclusive within block
  if (tid == 255) bsum[blockIdx.x] = lds[255];
}

// scan the (<=256) block sums; write total to ptr[N_NODES]
__global__ __launch_bounds__(256) void scan2_kernel(const int* __restrict__ bsum,
                                                    int* __restrict__ boff,
                                                    int* __restrict__ ptr,
                                                    int nb) {
  __shared__ int lds[256];
  const int tid = threadIdx.x;
  int v = (tid < nb) ? bsum[tid] : 0;
  lds[tid] = v;
  __syncthreads();
  for (int off = 1; off < 256; off <<= 1) {
    int t = (tid >= off) ? lds[tid - off] : 0;
    __syncthreads();
    lds[tid] += t;
    __syncthreads();
  }
  if (tid < nb) boff[tid] = lds[tid] - v;
  if (tid == 255) ptr[N_NODES] = lds[255];
}

__global__ __launch_bounds__(256) void scan3_kernel(int* __restrict__ ptr,
                                                    const int* __restrict__ boff) {
  int i = blockIdx.x * 256 + threadIdx.x;
  if (i < N_NODES) ptr[i] += boff[blockIdx.x];
}

__global__ __launch_bounds__(256) void fill_kernel(const int* __restrict__ src,
                                                   const int* __restrict__ dst,
                                                   int* __restrict__ cursor,
                                                   int* __restrict__ esrc) {
  int e = blockIdx.x * 256 + threadIdx.x;
  if (e < N_EDGES) {
    int pos = atomicAdd(&cursor[dst[e]], 1);
    esrc[pos] = src[e];
  }
}

// ---------------------------------------------------------------------------
// Pull aggregation, fused self-term. One wave per node.
// gather1: f32 in (x), bf16 out, C=128 (float2/lane)
// ---------------------------------------------------------------------------
__global__ __launch_bounds__(256) void gather1_kernel(
    const float* __restrict__ x, const int* __restrict__ ptr,
    const int* __restrict__ esrc, __hip_bfloat16* __restrict__ out) {
  const int wave = threadIdx.x >> 6;
  const int lane = threadIdx.x & 63;
  const int node = blockIdx.x * 4 + wave;
  if (node >= N_NODES) return;
  const int beg = ptr[node], end = ptr[node + 1];
  const float2* f2 = reinterpret_cast<const float2*>(x);
  float2 acc = f2[(size_t)node * 64 + lane];
  for (int e = beg; e < end; ++e) {
    int s = esrc[e];
    float2 v = f2[(size_t)s * 64 + lane];
    acc.x += v.x;
    acc.y += v.y;
  }
  ushort2 o = {f2bf(acc.x), f2bf(acc.y)};
  reinterpret_cast<ushort2*>(out)[(size_t)node * 64 + lane] = o;
}

// gather2: bf16 in/out, C=256 (ushort4/lane)
__global__ __launch_bounds__(256) void gather2_kernel(
    const __hip_bfloat16* __restrict__ h, const int* __restrict__ ptr,
    const int* __restrict__ esrc, __hip_bfloat16* __restrict__ out) {
  const int wave = threadIdx.x >> 6;
  const int lane = threadIdx.x & 63;
  const int node = blockIdx.x * 4 + wave;
  if (node >= N_NODES) return;
  const int beg = ptr[node], end = ptr[node + 1];
  const ushort4* u4 = reinterpret_cast<const ushort4*>(h);
  ushort4 sv = u4[(size_t)node * 64 + lane];
  float a0 = bf2f(sv.x), a1 = bf2f(sv.y), a2 = bf2f(sv.z), a3 = bf2f(sv.w);
  for (int e = beg; e < end; ++e) {
    int s = esrc[e];
    ushort4 v = u4[(size_t)s * 64 + lane];
    a0 += bf2f(v.x);
    a1 += bf2f(v.y);
    a2 += bf2f(v.z);
    a3 += bf2f(v.w);
  }
  ushort4 o = {f2bf(a0), f2bf(a1), f2bf(a2), f2bf(a3)};
  reinterpret_cast<ushort4*>(out)[(size_t)node * 64 + lane] = o;
}

// ---------------------------------------------------------------------------
// W [K][N] f32 -> Wt [N][K] bf16
// ---------------------------------------------------------------------------
__global__ __launch_bounds__(256) void convw_kernel(const float* __restrict__ W,
                                                    __hip_bfloat16* __restrict__ Wt,
                                                    int K, int N) {
  int idx = blockIdx.x * 256 + threadIdx.x;
  if (idx < K * N) {
    int k = idx / N, n = idx % N;
    Wt[(size_t)n * K + k] = __float2bfloat16(W[idx]);
  }
}

// ---------------------------------------------------------------------------
// MFMA GEMM: C[M][256] = act(A[M][K] @ W[K][256] + bias), A,W bf16, C bf16.
// Bt = W transposed [256][K]. 128x128 tile, 4 waves (2x2), BK=64 dbuf.
// LDS chunk swizzle: LDS[row][c] holds global chunk c ^ (row&7)
// (chunk = 16B = 8 bf16), applied by pre-swizzling the global source so
// global_load_lds (linear dest) + swizzled ds_read are consistent.
// ---------------------------------------------------------------------------
template <int K, bool RELU>
__global__ __launch_bounds__(256) void mfma_gemm_kernel(
    const __hip_bfloat16* __restrict__ A, const __hip_bfloat16* __restrict__ Bt,
    const float* __restrict__ bias, __hip_bfloat16* __restrict__ C, int M) {
  constexpr int BM = 128, BN = 128, BK = 64;
  constexpr int NT = K / BK;
  __shared__ char lds[2 * 2 * BM * BK * 2];  // 64 KB: 2 buf x (A 16K + B 16K)
  const int tid = threadIdx.x;
  const int l = tid & 63;
  const int w = tid >> 6;  // 0..3
  const int wr = w >> 1, wc = w & 1;
  const int row0 = blockIdx.x * BM;
  const int col0 = blockIdx.y * BN;

  const int srow = l >> 3;           // row within 8-row group (== row&7)
  const int scol = (l & 7) ^ srow;   // pre-swizzled source chunk

  f32x4 acc[4][4] = {};

  auto stage = [&](int buf, int t) {
    char* baseA = lds + buf * (32 * 1024);
    char* baseB = baseA + 16 * 1024;
#pragma unroll
    for (int i = 0; i < 4; ++i) {
      int rgrp = (i * 4 + w) * 8 + srow;  // tile row 0..127
      int ra = row0 + rgrp;
      if (ra > M - 1) ra = M - 1;
      load_lds16(A + (size_t)ra * K + t * BK + scol * 8,
                 baseA + (i * 4 + w) * 1024);
      int rb = col0 + rgrp;  // N=256 exact
      load_lds16(Bt + (size_t)rb * K + t * BK + scol * 8,
                 baseB + (i * 4 + w) * 1024);
    }
  };

  auto compute = [&](int buf) {
    char* baseA = lds + buf * (32 * 1024);
    char* baseB = baseA + 16 * 1024;
#pragma unroll
    for (int ks = 0; ks < 2; ++ks) {
      bf16x8 a[4], b[4];
      const int kc = ks * 4 + (l >> 4);
#pragma unroll
      for (int m = 0; m < 4; ++m) {
        int row = wr * 64 + m * 16 + (l & 15);
        a[m] = *reinterpret_cast<const bf16x8*>(
            baseA + (row * 8 + (kc ^ (row & 7))) * 16);
      }
#pragma unroll
      for (int n = 0; n < 4; ++n) {
        int row = wc * 64 + n * 16 + (l & 15);
        b[n] = *reinterpret_cast<const bf16x8*>(
            baseB + (row * 8 + (kc ^ (row & 7))) * 16);
      }
#pragma unroll
      for (int m = 0; m < 4; ++m)
#pragma unroll
        for (int n = 0; n < 4; ++n)
          acc[m][n] = __builtin_amdgcn_mfma_f32_16x16x32_bf16(a[m], b[n],
                                                              acc[m][n], 0, 0, 0);
    }
  };

  stage(0, 0);
  __syncthreads();  // compiler emits vmcnt(0) drain before barrier
  for (int t = 0; t < NT; ++t) {
    int cur = t & 1;
    if (t + 1 < NT) stage(cur ^ 1, t + 1);
    compute(cur);
    __syncthreads();
  }

  // epilogue: C/D layout col=lane&15, row=(lane>>4)*4+j
#pragma unroll
  for (int n = 0; n < 4; ++n) {
    int gc = col0 + wc * 64 + n * 16 + (l & 15);
    float bv = bias[gc];
#pragma unroll
    for (int m = 0; m < 4; ++m) {
      int rbase = row0 + wr * 64 + m * 16 + (l >> 4) * 4;
#pragma unroll
      for (int j = 0; j < 4; ++j) {
        int r = rbase + j;
        if (r < M) {
          float v = acc[m][n][j] + bv;
          if (RELU) v = fmaxf(v, 0.f);
          C[(size_t)r * 256 + gc] = __float2bfloat16(v);
        }
      }
    }
  }
}

// ---------------------------------------------------------------------------
// Mean-pool per graph (batch sorted). h bf16 -> hg f32.
// ---------------------------------------------------------------------------
__global__ __launch_bounds__(HID) void pool_kernel(
    const __hip_bfloat16* __restrict__ h, const int* __restrict__ batch,
    float* __restrict__ hgraph) {
  const int g = blockIdx.x;
  const int c = threadIdx.x;
  auto lower_bound = [&](int key) {
    int lo = 0, hi = N_NODES;
    while (lo < hi) {
      int mid = (lo + hi) >> 1;
      if (batch[mid] < key) lo = mid + 1; else hi = mid;
    }
    return lo;
  };
  const int s = lower_bound(g);
  const int e = lower_bound(g + 1);
  const unsigned short* hb = reinterpret_cast<const unsigned short*>(h);
  float acc = 0.f;
  for (int n = s; n < e; ++n) acc += bf2f(hb[(size_t)n * HID + c]);
  float cnt = fmaxf((float)(e - s), 1.0f);
  hgraph[g * HID + c] = acc / cnt;
}

// ---------------------------------------------------------------------------
// f32 row-block GEMM for the (tiny) projection head.
// ---------------------------------------------------------------------------
template <int K, int N, int R, bool RELU>
__global__ void gin_linear_kernel(const float* __restrict__ A,
                                  const float* __restrict__ W,
                                  const float* __restrict__ bias,
                                  float* __restrict__ Cout, int M) {
  __shared__ float As[R][K];
  const int row0 = blockIdx.x * R;
  const int tid = threadIdx.x;
  for (int idx = tid; idx < R * K; idx += N) {
    int r = idx / K, k = idx % K;
    int m = row0 + r;
    As[r][k] = (m < M) ? A[(size_t)m * K + k] : 0.f;
  }
  __syncthreads();
  float acc[R];
#pragma unroll
  for (int r = 0; r < R; ++r) acc[r] = bias[tid];
  for (int k = 0; k < K; ++k) {
    float w = W[k * N + tid];
#pragma unroll
    for (int r = 0; r < R; ++r) acc[r] = fmaf(As[r][k], w, acc[r]);
  }
#pragma unroll
  for (int r = 0; r < R; ++r) {
    int m = row0 + r;
    if (m < M) {
      float v = acc[r];
      if (RELU) v = fmaxf(v, 0.f);
      Cout[(size_t)m * N + tid] = v;
    }
  }
}

// ---------------------------------------------------------------------------
extern "C" void kernel_launch(void* const* d_in, const int* in_sizes, int n_in,
                              void* d_out, int out_size, void* d_ws,
                              size_t ws_size, hipStream_t stream) {
  const float* x = (const float*)d_in[0];
  const int* edge = (const int*)d_in[1];
  const int* batch = (const int*)d_in[2];
  const float* W1 = (const float*)d_in[3];
  const float* b1 = (const float*)d_in[4];
  const float* W2 = (const float*)d_in[5];
  const float* b2 = (const float*)d_in[6];
  const float* P1 = (const float*)d_in[7];
  const float* pb1 = (const float*)d_in[8];
  const float* P2 = (const float*)d_in[9];
  const float* pb2 = (const float*)d_in[10];
  const int* src = edge;
  const int* dst = edge + N_EDGES;

  char* ws = (char*)d_ws;
  size_t off = 0;
  auto alloc = [&](size_t bytes) {
    void* p = ws + off;
    off += (bytes + 255) & ~(size_t)255;
    return p;
  };
  __hip_bfloat16* xa  = (__hip_bfloat16*)alloc((size_t)N_NODES * IN_CH * 2);
  __hip_bfloat16* h1  = (__hip_bfloat16*)alloc((size_t)N_NODES * HID * 2);
  __hip_bfloat16* ha  = (__hip_bfloat16*)alloc((size_t)N_NODES * HID * 2);
  __hip_bfloat16* h2  = (__hip_bfloat16*)alloc((size_t)N_NODES * HID * 2);
  __hip_bfloat16* Wt1 = (__hip_bfloat16*)alloc((size_t)HID * IN_CH * 2);
  __hip_bfloat16* Wt2 = (__hip_bfloat16*)alloc((size_t)HID * HID * 2);
  float* hg = (float*)alloc((size_t)N_GRAPHS * HID * 4);
  float* t1 = (float*)alloc((size_t)N_GRAPHS * HID * 4);
  int* ptr = (int*)alloc((size_t)(N_NODES + 1) * 4);
  int* cursor = (int*)alloc((size_t)N_NODES * 4);  // count buf, then cursors
  int* esrc = (int*)alloc((size_t)N_EDGES * 4);
  int* bsum = (int*)alloc(256 * 4);
  int* boff = (int*)alloc(256 * 4);
  float* z = (float*)d_out;

  const int EB = (N_EDGES + 255) / 256;
  const int NB = (N_NODES + 255) / 256;  // 196

  // --- CSR build (dst-indexed) ---
  hipMemsetAsync(cursor, 0, (size_t)N_NODES * 4, stream);
  count_kernel<<<EB, 256, 0, stream>>>(dst, cursor);
  scan1_kernel<<<NB, 256, 0, stream>>>(cursor, ptr, bsum);
  scan2_kernel<<<1, 256, 0, stream>>>(bsum, boff, ptr, NB);
  scan3_kernel<<<NB, 256, 0, stream>>>(ptr, boff);
  hipMemcpyAsync(cursor, ptr, (size_t)N_NODES * 4, hipMemcpyDeviceToDevice, stream);
  fill_kernel<<<EB, 256, 0, stream>>>(src, dst, cursor, esrc);

  // --- weight prep ---
  convw_kernel<<<(IN_CH * HID + 255) / 256, 256, 0, stream>>>(W1, Wt1, IN_CH, HID);
  convw_kernel<<<(HID * HID + 255) / 256, 256, 0, stream>>>(W2, Wt2, HID, HID);

  // --- Layer 1 ---
  gather1_kernel<<<(N_NODES + 3) / 4, 256, 0, stream>>>(x, ptr, esrc, xa);
  {
    dim3 grid((N_NODES + 127) / 128, HID / 128);
    mfma_gemm_kernel<IN_CH, true><<<grid, 256, 0, stream>>>(xa, Wt1, b1, h1, N_NODES);
  }

  // --- Layer 2 ---
  gather2_kernel<<<(N_NODES + 3) / 4, 256, 0, stream>>>(h1, ptr, esrc, ha);
  {
    dim3 grid((N_NODES + 127) / 128, HID / 128);
    mfma_gemm_kernel<HID, true><<<grid, 256, 0, stream>>>(ha, Wt2, b2, h2, N_NODES);
  }

  // --- Mean pool ---
  pool_kernel<<<N_GRAPHS, HID, 0, stream>>>(h2, batch, hg);

  // --- Projection head (f32, tiny) ---
  gin_linear_kernel<HID, HID, 8, true>
      <<<(N_GRAPHS + 7) / 8, HID, 0, stream>>>(hg, P1, pb1, t1, N_GRAPHS);
  gin_linear_kernel<HID, PROJ, 8, false>
      <<<(N_GRAPHS + 7) / 8, PROJ, 0, stream>>>(t1, P2, pb2, z, N_GRAPHS);
}

// Round 4
// 335.394 us; speedup vs baseline: 12.8418x; 1.2546x over previous
//
#include <hip/hip_runtime.h>
#include <hip/hip_bf16.h>

#define N_NODES 50000
#define N_EDGES 800000
#define IN_CH 128
#define HID 256
#define PROJ 128
#define N_GRAPHS 512

typedef short bf16x8 __attribute__((ext_vector_type(8)));
typedef float f32x4 __attribute__((ext_vector_type(4)));

__device__ inline float bf2f(unsigned short u) {
  union { unsigned int i; float f; } x;
  x.i = ((unsigned int)u) << 16;
  return x.f;
}
__device__ inline unsigned short f2bf(float f) {
  __hip_bfloat16 h = __float2bfloat16(f);  // RNE
  return *reinterpret_cast<unsigned short*>(&h);
}
__device__ inline void load_lds16(const void* g, void* l) {
  __builtin_amdgcn_global_load_lds(
      (const __attribute__((address_space(1))) void*)g,
      (__attribute__((address_space(3))) void*)l, 16, 0, 0);
}

// ---------------------------------------------------------------------------
// CSR build
// ---------------------------------------------------------------------------
__global__ __launch_bounds__(256) void count_kernel(const int* __restrict__ dst,
                                                    int* __restrict__ cnt) {
  int e = blockIdx.x * 256 + threadIdx.x;
  if (e < N_EDGES) atomicAdd(&cnt[dst[e]], 1);
}

__global__ __launch_bounds__(256) void scan1_kernel(const int* __restrict__ cnt,
                                                    int* __restrict__ ptr,
                                                    int* __restrict__ bsum) {
  __shared__ int lds[256];
  const int tid = threadIdx.x;
  const int i = blockIdx.x * 256 + tid;
  int v = (i < N_NODES) ? cnt[i] : 0;
  lds[tid] = v;
  __syncthreads();
  for (int off = 1; off < 256; off <<= 1) {
    int t = (tid >= off) ? lds[tid - off] : 0;
    __syncthreads();
    lds[tid] += t;
    __syncthreads();
  }
  if (i < N_NODES) ptr[i] = lds[tid] - v;  // exclusive within block
  if (tid == 255) bsum[blockIdx.x] = lds[255];
}

__global__ __launch_bounds__(256) void scan2_kernel(const int* __restrict__ bsum,
                                                    int* __restrict__ boff,
                                                    int* __restrict__ ptr,
                                                    int nb) {
  __shared__ int lds[256];
  const int tid = threadIdx.x;
  int v = (tid < nb) ? bsum[tid] : 0;
  lds[tid] = v;
  __syncthreads();
  for (int off = 1; off < 256; off <<= 1) {
    int t = (tid >= off) ? lds[tid - off] : 0;
    __syncthreads();
    lds[tid] += t;
    __syncthreads();
  }
  if (tid < nb) boff[tid] = lds[tid] - v;
  if (tid == 255) ptr[N_NODES] = lds[255];
}

__global__ __launch_bounds__(256) void scan3_kernel(int* __restrict__ ptr,
                                                    const int* __restrict__ boff) {
  int i = blockIdx.x * 256 + threadIdx.x;
  if (i < N_NODES) ptr[i] += boff[blockIdx.x];
}

__global__ __launch_bounds__(256) void fill_kernel(const int* __restrict__ src,
                                                   const int* __restrict__ dst,
                                                   int* __restrict__ cursor,
                                                   int* __restrict__ esrc) {
  int e = blockIdx.x * 256 + threadIdx.x;
  if (e < N_EDGES) {
    int pos = atomicAdd(&cursor[dst[e]], 1);
    esrc[pos] = src[e];
  }
}

// ---------------------------------------------------------------------------
// x f32 -> bf16 (so the layer-1 gather moves half the bytes)
// ---------------------------------------------------------------------------
__global__ __launch_bounds__(256) void convx_kernel(const float* __restrict__ x,
                                                    __hip_bfloat16* __restrict__ xb) {
  int idx = blockIdx.x * 256 + threadIdx.x;  // float4 units
  const int total = N_NODES * IN_CH / 4;
  if (idx < total) {
    float4 v = reinterpret_cast<const float4*>(x)[idx];
    ushort4 o = {f2bf(v.x), f2bf(v.y), f2bf(v.z), f2bf(v.w)};
    reinterpret_cast<ushort4*>(xb)[idx] = o;
  }
}

// ---------------------------------------------------------------------------
// Pull aggregation, fused self-term, one wave per node, 4x unrolled gather.
// gather1: bf16 in/out, C=128 (ushort2/lane)
// ---------------------------------------------------------------------------
__global__ __launch_bounds__(256) void gather1_kernel(
    const __hip_bfloat16* __restrict__ xb, const int* __restrict__ ptr,
    const int* __restrict__ esrc, __hip_bfloat16* __restrict__ out) {
  const int wave = threadIdx.x >> 6;
  const int lane = threadIdx.x & 63;
  const int node = blockIdx.x * 4 + wave;
  if (node >= N_NODES) return;
  const int beg = __builtin_amdgcn_readfirstlane(ptr[node]);
  const int end = __builtin_amdgcn_readfirstlane(ptr[node + 1]);
  const ushort2* u2 = reinterpret_cast<const ushort2*>(xb);
  ushort2 sv = u2[(size_t)node * 64 + lane];
  float a0 = bf2f(sv.x), a1 = bf2f(sv.y);
  int e = beg;
  for (; e + 4 <= end; e += 4) {
    int s0 = esrc[e], s1 = esrc[e + 1], s2 = esrc[e + 2], s3 = esrc[e + 3];
    ushort2 v0 = u2[(size_t)s0 * 64 + lane];
    ushort2 v1 = u2[(size_t)s1 * 64 + lane];
    ushort2 v2 = u2[(size_t)s2 * 64 + lane];
    ushort2 v3 = u2[(size_t)s3 * 64 + lane];
    a0 += bf2f(v0.x) + bf2f(v1.x) + bf2f(v2.x) + bf2f(v3.x);
    a1 += bf2f(v0.y) + bf2f(v1.y) + bf2f(v2.y) + bf2f(v3.y);
  }
  for (; e < end; ++e) {
    int s = esrc[e];
    ushort2 v = u2[(size_t)s * 64 + lane];
    a0 += bf2f(v.x);
    a1 += bf2f(v.y);
  }
  ushort2 o = {f2bf(a0), f2bf(a1)};
  reinterpret_cast<ushort2*>(out)[(size_t)node * 64 + lane] = o;
}

// gather2: bf16 in/out, C=256 (ushort4/lane), 4x unrolled
__global__ __launch_bounds__(256) void gather2_kernel(
    const __hip_bfloat16* __restrict__ h, const int* __restrict__ ptr,
    const int* __restrict__ esrc, __hip_bfloat16* __restrict__ out) {
  const int wave = threadIdx.x >> 6;
  const int lane = threadIdx.x & 63;
  const int node = blockIdx.x * 4 + wave;
  if (node >= N_NODES) return;
  const int beg = __builtin_amdgcn_readfirstlane(ptr[node]);
  const int end = __builtin_amdgcn_readfirstlane(ptr[node + 1]);
  const ushort4* u4 = reinterpret_cast<const ushort4*>(h);
  ushort4 sv = u4[(size_t)node * 64 + lane];
  float a0 = bf2f(sv.x), a1 = bf2f(sv.y), a2 = bf2f(sv.z), a3 = bf2f(sv.w);
  int e = beg;
  for (; e + 4 <= end; e += 4) {
    int s0 = esrc[e], s1 = esrc[e + 1], s2 = esrc[e + 2], s3 = esrc[e + 3];
    ushort4 v0 = u4[(size_t)s0 * 64 + lane];
    ushort4 v1 = u4[(size_t)s1 * 64 + lane];
    ushort4 v2 = u4[(size_t)s2 * 64 + lane];
    ushort4 v3 = u4[(size_t)s3 * 64 + lane];
    a0 += bf2f(v0.x) + bf2f(v1.x) + bf2f(v2.x) + bf2f(v3.x);
    a1 += bf2f(v0.y) + bf2f(v1.y) + bf2f(v2.y) + bf2f(v3.y);
    a2 += bf2f(v0.z) + bf2f(v1.z) + bf2f(v2.z) + bf2f(v3.z);
    a3 += bf2f(v0.w) + bf2f(v1.w) + bf2f(v2.w) + bf2f(v3.w);
  }
  for (; e < end; ++e) {
    int s = esrc[e];
    ushort4 v = u4[(size_t)s * 64 + lane];
    a0 += bf2f(v.x);
    a1 += bf2f(v.y);
    a2 += bf2f(v.z);
    a3 += bf2f(v.w);
  }
  ushort4 o = {f2bf(a0), f2bf(a1), f2bf(a2), f2bf(a3)};
  reinterpret_cast<ushort4*>(out)[(size_t)node * 64 + lane] = o;
}

// ---------------------------------------------------------------------------
// W [K][N] f32 -> Wt [N][K] bf16
// ---------------------------------------------------------------------------
__global__ __launch_bounds__(256) void convw_kernel(const float* __restrict__ W,
                                                    __hip_bfloat16* __restrict__ Wt,
                                                    int K, int N) {
  int idx = blockIdx.x * 256 + threadIdx.x;
  if (idx < K * N) {
    int k = idx / N, n = idx % N;
    Wt[(size_t)n * K + k] = __float2bfloat16(W[idx]);
  }
}

// ---------------------------------------------------------------------------
// MFMA GEMM: C[M][256] = act(A[M][K] @ W[K][256] + bias), A,W bf16, C bf16.
// 128x128 tile, 4 waves (2x2), BK=64 dbuf, global_load_lds w/ pre-swizzled src.
// ---------------------------------------------------------------------------
template <int K, bool RELU>
__global__ __launch_bounds__(256) void mfma_gemm_kernel(
    const __hip_bfloat16* __restrict__ A, const __hip_bfloat16* __restrict__ Bt,
    const float* __restrict__ bias, __hip_bfloat16* __restrict__ C, int M) {
  constexpr int BM = 128, BN = 128, BK = 64;
  constexpr int NT = K / BK;
  __shared__ char lds[2 * 2 * BM * BK * 2];  // 64 KB
  const int tid = threadIdx.x;
  const int l = tid & 63;
  const int w = tid >> 6;
  const int wr = w >> 1, wc = w & 1;
  const int row0 = blockIdx.x * BM;
  const int col0 = blockIdx.y * BN;

  const int srow = l >> 3;
  const int scol = (l & 7) ^ srow;

  f32x4 acc[4][4] = {};

  auto stage = [&](int buf, int t) {
    char* baseA = lds + buf * (32 * 1024);
    char* baseB = baseA + 16 * 1024;
#pragma unroll
    for (int i = 0; i < 4; ++i) {
      int rgrp = (i * 4 + w) * 8 + srow;
      int ra = row0 + rgrp;
      if (ra > M - 1) ra = M - 1;
      load_lds16(A + (size_t)ra * K + t * BK + scol * 8,
                 baseA + (i * 4 + w) * 1024);
      int rb = col0 + rgrp;
      load_lds16(Bt + (size_t)rb * K + t * BK + scol * 8,
                 baseB + (i * 4 + w) * 1024);
    }
  };

  auto compute = [&](int buf) {
    char* baseA = lds + buf * (32 * 1024);
    char* baseB = baseA + 16 * 1024;
#pragma unroll
    for (int ks = 0; ks < 2; ++ks) {
      bf16x8 a[4], b[4];
      const int kc = ks * 4 + (l >> 4);
#pragma unroll
      for (int m = 0; m < 4; ++m) {
        int row = wr * 64 + m * 16 + (l & 15);
        a[m] = *reinterpret_cast<const bf16x8*>(
            baseA + (row * 8 + (kc ^ (row & 7))) * 16);
      }
#pragma unroll
      for (int n = 0; n < 4; ++n) {
        int row = wc * 64 + n * 16 + (l & 15);
        b[n] = *reinterpret_cast<const bf16x8*>(
            baseB + (row * 8 + (kc ^ (row & 7))) * 16);
      }
#pragma unroll
      for (int m = 0; m < 4; ++m)
#pragma unroll
        for (int n = 0; n < 4; ++n)
          acc[m][n] = __builtin_amdgcn_mfma_f32_16x16x32_bf16(a[m], b[n],
                                                              acc[m][n], 0, 0, 0);
    }
  };

  stage(0, 0);
  __syncthreads();
  for (int t = 0; t < NT; ++t) {
    int cur = t & 1;
    if (t + 1 < NT) stage(cur ^ 1, t + 1);
    compute(cur);
    __syncthreads();
  }

#pragma unroll
  for (int n = 0; n < 4; ++n) {
    int gc = col0 + wc * 64 + n * 16 + (l & 15);
    float bv = bias[gc];
#pragma unroll
    for (int m = 0; m < 4; ++m) {
      int rbase = row0 + wr * 64 + m * 16 + (l >> 4) * 4;
#pragma unroll
      for (int j = 0; j < 4; ++j) {
        int r = rbase + j;
        if (r < M) {
          float v = acc[m][n][j] + bv;
          if (RELU) v = fmaxf(v, 0.f);
          C[(size_t)r * 256 + gc] = __float2bfloat16(v);
        }
      }
    }
  }
}

// ---------------------------------------------------------------------------
// Mean-pool per graph (batch sorted). h bf16 -> hg f32.
// ---------------------------------------------------------------------------
__global__ __launch_bounds__(HID) void pool_kernel(
    const __hip_bfloat16* __restrict__ h, const int* __restrict__ batch,
    float* __restrict__ hgraph) {
  const int g = blockIdx.x;
  const int c = threadIdx.x;
  auto lower_bound = [&](int key) {
    int lo = 0, hi = N_NODES;
    while (lo < hi) {
      int mid = (lo + hi) >> 1;
      if (batch[mid] < key) lo = mid + 1; else hi = mid;
    }
    return lo;
  };
  const int s = lower_bound(g);
  const int e = lower_bound(g + 1);
  const unsigned short* hb = reinterpret_cast<const unsigned short*>(h);
  float acc = 0.f;
  for (int n = s; n < e; ++n) acc += bf2f(hb[(size_t)n * HID + c]);
  float cnt = fmaxf((float)(e - s), 1.0f);
  hgraph[g * HID + c] = acc / cnt;
}

// ---------------------------------------------------------------------------
// f32 row-block GEMM for the (tiny) projection head.
// ---------------------------------------------------------------------------
template <int K, int N, int R, bool RELU>
__global__ void gin_linear_kernel(const float* __restrict__ A,
                                  const float* __restrict__ W,
                                  const float* __restrict__ bias,
                                  float* __restrict__ Cout, int M) {
  __shared__ float As[R][K];
  const int row0 = blockIdx.x * R;
  const int tid = threadIdx.x;
  for (int idx = tid; idx < R * K; idx += N) {
    int r = idx / K, k = idx % K;
    int m = row0 + r;
    As[r][k] = (m < M) ? A[(size_t)m * K + k] : 0.f;
  }
  __syncthreads();
  float acc[R];
#pragma unroll
  for (int r = 0; r < R; ++r) acc[r] = bias[tid];
  for (int k = 0; k < K; ++k) {
    float w = W[k * N + tid];
#pragma unroll
    for (int r = 0; r < R; ++r) acc[r] = fmaf(As[r][k], w, acc[r]);
  }
#pragma unroll
  for (int r = 0; r < R; ++r) {
    int m = row0 + r;
    if (m < M) {
      float v = acc[r];
      if (RELU) v = fmaxf(v, 0.f);
      Cout[(size_t)m * N + tid] = v;
    }
  }
}

// ---------------------------------------------------------------------------
extern "C" void kernel_launch(void* const* d_in, const int* in_sizes, int n_in,
                              void* d_out, int out_size, void* d_ws,
                              size_t ws_size, hipStream_t stream) {
  const float* x = (const float*)d_in[0];
  const int* edge = (const int*)d_in[1];
  const int* batch = (const int*)d_in[2];
  const float* W1 = (const float*)d_in[3];
  const float* b1 = (const float*)d_in[4];
  const float* W2 = (const float*)d_in[5];
  const float* b2 = (const float*)d_in[6];
  const float* P1 = (const float*)d_in[7];
  const float* pb1 = (const float*)d_in[8];
  const float* P2 = (const float*)d_in[9];
  const float* pb2 = (const float*)d_in[10];
  const int* src = edge;
  const int* dst = edge + N_EDGES;

  char* ws = (char*)d_ws;
  size_t off = 0;
  auto alloc = [&](size_t bytes) {
    void* p = ws + off;
    off += (bytes + 255) & ~(size_t)255;
    return p;
  };
  __hip_bfloat16* xb  = (__hip_bfloat16*)alloc((size_t)N_NODES * IN_CH * 2);
  __hip_bfloat16* xa  = (__hip_bfloat16*)alloc((size_t)N_NODES * IN_CH * 2);
  __hip_bfloat16* h1  = (__hip_bfloat16*)alloc((size_t)N_NODES * HID * 2);
  __hip_bfloat16* ha  = (__hip_bfloat16*)alloc((size_t)N_NODES * HID * 2);
  __hip_bfloat16* h2  = (__hip_bfloat16*)alloc((size_t)N_NODES * HID * 2);
  __hip_bfloat16* Wt1 = (__hip_bfloat16*)alloc((size_t)HID * IN_CH * 2);
  __hip_bfloat16* Wt2 = (__hip_bfloat16*)alloc((size_t)HID * HID * 2);
  float* hg = (float*)alloc((size_t)N_GRAPHS * HID * 4);
  float* t1 = (float*)alloc((size_t)N_GRAPHS * HID * 4);
  int* ptr = (int*)alloc((size_t)(N_NODES + 1) * 4);
  int* cursor = (int*)alloc((size_t)N_NODES * 4);
  int* esrc = (int*)alloc((size_t)N_EDGES * 4);
  int* bsum = (int*)alloc(256 * 4);
  int* boff = (int*)alloc(256 * 4);
  float* z = (float*)d_out;

  const int EB = (N_EDGES + 255) / 256;
  const int NB = (N_NODES + 255) / 256;  // 196

  // --- CSR build (dst-indexed) ---
  hipMemsetAsync(cursor, 0, (size_t)N_NODES * 4, stream);
  count_kernel<<<EB, 256, 0, stream>>>(dst, cursor);
  scan1_kernel<<<NB, 256, 0, stream>>>(cursor, ptr, bsum);
  scan2_kernel<<<1, 256, 0, stream>>>(bsum, boff, ptr, NB);
  scan3_kernel<<<NB, 256, 0, stream>>>(ptr, boff);
  hipMemcpyAsync(cursor, ptr, (size_t)N_NODES * 4, hipMemcpyDeviceToDevice, stream);
  fill_kernel<<<EB, 256, 0, stream>>>(src, dst, cursor, esrc);

  // --- weight/feature prep ---
  convx_kernel<<<(N_NODES * IN_CH / 4 + 255) / 256, 256, 0, stream>>>(x, xb);
  convw_kernel<<<(IN_CH * HID + 255) / 256, 256, 0, stream>>>(W1, Wt1, IN_CH, HID);
  convw_kernel<<<(HID * HID + 255) / 256, 256, 0, stream>>>(W2, Wt2, HID, HID);

  // --- Layer 1 ---
  gather1_kernel<<<(N_NODES + 3) / 4, 256, 0, stream>>>(xb, ptr, esrc, xa);
  {
    dim3 grid((N_NODES + 127) / 128, HID / 128);
    mfma_gemm_kernel<IN_CH, true><<<grid, 256, 0, stream>>>(xa, Wt1, b1, h1, N_NODES);
  }

  // --- Layer 2 ---
  gather2_kernel<<<(N_NODES + 3) / 4, 256, 0, stream>>>(h1, ptr, esrc, ha);
  {
    dim3 grid((N_NODES + 127) / 128, HID / 128);
    mfma_gemm_kernel<HID, true><<<grid, 256, 0, stream>>>(ha, Wt2, b2, h2, N_NODES);
  }

  // --- Mean pool ---
  pool_kernel<<<N_GRAPHS, HID, 0, stream>>>(h2, batch, hg);

  // --- Projection head (f32, tiny) ---
  gin_linear_kernel<HID, HID, 8, true>
      <<<(N_GRAPHS + 7) / 8, HID, 0, stream>>>(hg, P1, pb1, t1, N_GRAPHS);
  gin_linear_kernel<HID, PROJ, 8, false>
      <<<(N_GRAPHS + 7) / 8, PROJ, 0, stream>>>(t1, P2, pb2, z, N_GRAPHS);
}